// Round 13
// baseline (197.582 us; speedup 1.0000x reference)
//
#include <hip/hip_runtime.h>
#include <hip/hip_fp16.h>
#include <math.h>

#define N_NODES 100000
#define N_EDGES 1600000
#define E_TOT (N_EDGES + N_NODES)   // self-loops injected as virtual edges
#define IN_FEAT 16
#define OUT_FEAT 16
#define HEADS 6
#define HF 96                 // HEADS*OUT_FEAT

// Bucketed-aggregate geometry:
#define NB 4096               // histogram bins in prep (4000 used)
#define NBA 4000              // active buckets (4000*25 = 100000 exactly)
#define NPB 25                // nodes per bucket
#define CAP 576               // per-bucket capacity: mean 425 incl self, +7.3 sigma
#define MAXDEG 64             // per-node slot capacity (1+Poisson(16): P(>=63) ~ 1e-20)
#define NBLK_PART 256         // partition blocks
#define NT_BLOCKS ((N_NODES * HEADS + 255) / 256)

static __device__ __forceinline__ unsigned int pk2h(float a, float b) {
    return (unsigned int)__half_as_ushort(__float2half_rn(a))
         | ((unsigned int)__half_as_ushort(__float2half_rn(b)) << 16);
}
static __device__ __forceinline__ float uph_lo(unsigned int w) {
    return __half2float(__ushort_as_half((unsigned short)(w & 0xFFFFu)));
}
static __device__ __forceinline__ float uph_hi(unsigned int w) {
    return __half2float(__ushort_as_half((unsigned short)(w >> 16)));
}

// ---------------------------------------------------------------------------
// K1: prep = partition (blocks [0,NBLK_PART)) + node_transform (rest).
// Unchanged from R12. spack[pos] = src | (d_local << 17).
// ---------------------------------------------------------------------------
__global__ void prep(const int* __restrict__ esrc,
                     const int* __restrict__ edst,
                     int* __restrict__ gcursor,
                     unsigned int* __restrict__ spack,
                     const float* __restrict__ data,
                     const float* __restrict__ W,
                     const float* __restrict__ att_src,
                     const float* __restrict__ att_dst,
                     float* __restrict__ a_src,
                     float* __restrict__ a_dst,
                     unsigned short* __restrict__ data_f16) {
    __shared__ int shmem[2 * NB];   // 32 KB

    if (blockIdx.x < NBLK_PART) {
        // ---------------- partition branch ----------------
        int* hist = shmem;
        int* base = shmem + NB;
        const int chunk = (E_TOT + NBLK_PART - 1) / NBLK_PART;   // 6641
        const int e0 = blockIdx.x * chunk;
        const int e1 = min(e0 + chunk, E_TOT);

        for (int j = threadIdx.x; j < NB; j += blockDim.x) hist[j] = 0;
        __syncthreads();
        for (int e = e0 + threadIdx.x; e < e1; e += blockDim.x) {
            int d = (e < N_EDGES) ? edst[e] : (e - N_EDGES);
            atomicAdd(&hist[d / NPB], 1);      // native int ds_add
        }
        __syncthreads();
        for (int j = threadIdx.x; j < NB; j += blockDim.x) {
            int c = hist[j];
            base[j] = c ? atomicAdd(&gcursor[j], c) : 0;
        }
        __syncthreads();
        for (int j = threadIdx.x; j < NB; j += blockDim.x) hist[j] = 0;
        __syncthreads();
        for (int e = e0 + threadIdx.x; e < e1; e += blockDim.x) {
            int s, d;
            if (e < N_EDGES) { s = esrc[e]; d = edst[e]; }
            else             { s = d = e - N_EDGES; }
            int b = d / NPB;
            int r = atomicAdd(&hist[b], 1);
            int pos = b * CAP + base[b] + r;
            if (pos < (b + 1) * CAP)           // statistically unreachable
                spack[pos] = (unsigned int)s | ((unsigned int)(d - b * NPB) << 17);
        }
    } else {
        // ---------------- node_transform branch ----------------
        float* sW  = (float*)shmem;            // 1536 floats
        float* sAs = sW + IN_FEAT * HF;        // 96
        float* sAd = sAs + HF;                 // 96
        for (int i = threadIdx.x; i < IN_FEAT * HF; i += blockDim.x) sW[i] = W[i];
        for (int i = threadIdx.x; i < HF; i += blockDim.x) { sAs[i] = att_src[i]; sAd[i] = att_dst[i]; }
        __syncthreads();

        int gid = (blockIdx.x - NBLK_PART) * blockDim.x + threadIdx.x;
        int n = gid / HEADS;
        int h = gid % HEADS;
        if (n >= N_NODES) return;

        float dv[IN_FEAT];
        const float4* dp = (const float4*)(data + (size_t)n * IN_FEAT);
#pragma unroll
        for (int q = 0; q < 4; q++) {
            float4 v = dp[q];
            dv[q*4+0] = v.x; dv[q*4+1] = v.y; dv[q*4+2] = v.z; dv[q*4+3] = v.w;
        }

        // emit f16 copy of the row (threads h=0..3 each pack 4 halves)
        if (h < 4) {
            uint2 pkd;
            pkd.x = pk2h(dv[h*4+0], dv[h*4+1]);
            pkd.y = pk2h(dv[h*4+2], dv[h*4+3]);
            *(uint2*)(data_f16 + (size_t)n * IN_FEAT + h * 4) = pkd;
        }

        float outv[OUT_FEAT];
#pragma unroll
        for (int fo = 0; fo < OUT_FEAT; fo++) outv[fo] = 0.f;
#pragma unroll
        for (int k = 0; k < IN_FEAT; k++) {
            float dk = dv[k];
            const float* wrow = &sW[k * HF + h * OUT_FEAT];
#pragma unroll
            for (int fo = 0; fo < OUT_FEAT; fo++) outv[fo] = fmaf(dk, wrow[fo], outv[fo]);
        }

        float as = 0.f, ad = 0.f;
#pragma unroll
        for (int fo = 0; fo < OUT_FEAT; fo++) {
            as = fmaf(outv[fo], sAs[h * OUT_FEAT + fo], as);
            ad = fmaf(outv[fo], sAd[h * OUT_FEAT + fo], ad);
        }
        a_src[n * HEADS + h] = as;
        a_dst[n * HEADS + h] = ad;
    }
}

// ---------------------------------------------------------------------------
// K2: edge_ex — flat, massively-parallel per-edge attention weights.
// (R12 lesson: the 6 gathers + 6 exp chains per edge cost ~30 of 50 hot-loop
// VALU instrs inside a 40%-occupancy kernel; flat kernels here run at ~80%.)
// One thread per spack slot: ex[h] = exp(leakyrelu(a_src[s,h]+a_dst[d,h])),
// 6 f16 packed into one 16B record (uint4 store, fully coalesced).
// ---------------------------------------------------------------------------
__global__ void edge_ex(const int* __restrict__ gcursor,
                        const unsigned int* __restrict__ spack,
                        const float* __restrict__ a_src,
                        const float* __restrict__ a_dst,
                        unsigned short* __restrict__ exf) {
    int tid = blockIdx.x * 256 + threadIdx.x;     // < NBA*CAP
    int b = tid / CAP;
    int i = tid - b * CAP;
    int ecnt = gcursor[b];
    if (ecnt > CAP) ecnt = CAP;
    if (i >= ecnt) return;

    unsigned int p = spack[tid];
    int s = (int)(p & 0x1FFFFu);
    int d = b * NPB + (int)(p >> 17);

    float ex[HEADS];
#pragma unroll
    for (int h = 0; h < HEADS; h++) {
        float e = a_src[s * HEADS + h] + a_dst[d * HEADS + h];
        e = e > 0.f ? e : 0.2f * e;               // leaky relu
        ex[h] = __expf(e);
    }
    uint4 v;
    v.x = pk2h(ex[0], ex[1]);
    v.y = pk2h(ex[2], ex[3]);
    v.z = pk2h(ex[4], ex[5]);
    v.w = 0;
    *(uint4*)(exf + (size_t)tid * 8) = v;
}

// ---------------------------------------------------------------------------
// K3: bucket accumulate v5 — slim hot loop (exp precomputed by edge_ex).
// Binning packs s | (i<<17) so phase A can address exf[b*CAP+i].
// Phase A per edge-iter: 1 ds_read + 1 uint4 exf load + 1 ushort data load
// + ~20 VALU (6 cvt, 6 fma, 6 add). Live state ~35 VGPR -> (256,8) fits the
// 64-VGPR budget (R11's spill was the old fat loop), giving 8 waves/SIMD.
// ---------------------------------------------------------------------------
__global__ __launch_bounds__(256, 8)
void bucket_accumulate(const int* __restrict__ gcursor,
                       const unsigned int* __restrict__ spack,
                       const float* __restrict__ data,
                       const unsigned short* __restrict__ data_f16,
                       const unsigned short* __restrict__ exf,
                       const float* __restrict__ W,
                       const float* __restrict__ bias,
                       float* __restrict__ out) {
    const int b = blockIdx.x;
    const int n0 = b * NPB;
    __shared__ unsigned int olist[NPB * MAXDEG];   // 6.4 KB
    __shared__ float wsn_l[NPB * 100];             // 10 KB, pad stride 100
    __shared__ int cnt[NPB];
    __shared__ int nidx;

    const int tid  = threadIdx.x;
    const int lane = tid & 63;
    const int slot = lane >> 4;       // 4 edge-slots per wave
    const int f    = lane & 15;       // feature index

    int ecnt = gcursor[b];
    if (ecnt > CAP) ecnt = CAP;

    for (int j = tid; j < NPB; j += 256) cnt[j] = 0;
    if (tid == 0) nidx = 0;
    __syncthreads();

    // ---- single-pass bin into fixed per-node slots ----
    for (int i = tid; i < ecnt; i += 256) {
        unsigned int p = spack[b * CAP + i];
        int dl = (int)(p >> 17);
        int r = atomicAdd(&cnt[dl], 1);
        if (r < MAXDEG)                // statistically unreachable guard
            olist[dl * MAXDEG + r] = (p & 0x1FFFFu) | ((unsigned int)i << 17);
    }
    __syncthreads();

    // ---- phase A: dynamic node->wave assignment, slim loop ----
    for (;;) {
        int my;
        if (lane == 0) my = atomicAdd(&nidx, 1);
        my = __builtin_amdgcn_readfirstlane(my);
        if (my >= NPB) break;

        int T = cnt[my];
        if (T > MAXDEG) T = MAXDEG;
        const unsigned int* ol = olist + my * MAXDEG;

        float ws[HEADS], dn[HEADS];
#pragma unroll
        for (int h = 0; h < HEADS; h++) { ws[h] = 0.f; dn[h] = 0.f; }

        for (int t = slot; t < T; t += 4) {
            unsigned int e = ol[t];
            int s = (int)(e & 0x1FFFFu);
            int i = (int)(e >> 17);
            uint4 ev = *(const uint4*)(exf + ((size_t)b * CAP + i) * 8);
            float dv = __half2float(__ushort_as_half(data_f16[(size_t)s * IN_FEAT + f]));
            float e0 = uph_lo(ev.x), e1 = uph_hi(ev.x);
            float e2 = uph_lo(ev.y), e3 = uph_hi(ev.y);
            float e4 = uph_lo(ev.z), e5 = uph_hi(ev.z);
            ws[0] = fmaf(dv, e0, ws[0]); dn[0] += e0;
            ws[1] = fmaf(dv, e1, ws[1]); dn[1] += e1;
            ws[2] = fmaf(dv, e2, ws[2]); dn[2] += e2;
            ws[3] = fmaf(dv, e3, ws[3]); dn[3] += e3;
            ws[4] = fmaf(dv, e4, ws[4]); dn[4] += e4;
            ws[5] = fmaf(dv, e5, ws[5]); dn[5] += e5;
        }

        // butterfly over the 4 slots -> every lane holds totals
#pragma unroll
        for (int h = 0; h < HEADS; h++) {
            ws[h] += __shfl_xor(ws[h], 16);
            ws[h] += __shfl_xor(ws[h], 32);
            dn[h] += __shfl_xor(dn[h], 16);
            dn[h] += __shfl_xor(dn[h], 32);
        }

        if (slot == 0) {
            const int n = n0 + my;
            float cs = 0.f;
#pragma unroll
            for (int h = 0; h < HEADS; h++) {
                float wsn = ws[h] * __builtin_amdgcn_rcpf(dn[h] + 1e-16f);
                cs += wsn;
                wsn_l[my * 100 + h * 16 + f] = wsn;
            }
            if (f < 2) {                      // fused coord output (f32 key!)
                float c = cs * (0.2f / 6.f);
                float key = data[(size_t)n * IN_FEAT + f];
                if (key == 1.0f)      c = 1.0f;
                else if (key == 0.0f) c = 0.0f;
                out[n * 2 + f] = c;
            }
        }
    }
    __syncthreads();

    // ---- phase B: dense per-node transform; W via L1 (6 KB, hot) ----
    const float sc = 1.0507009873554805f;
    const float al = 1.6732632423543772f;
    for (int task = tid; task < NPB * 16; task += 256) {
        int dl = task >> 4, fo = task & 15;
        float acc = 0.f;
#pragma unroll
        for (int h = 0; h < HEADS; h++) {
            const float* wr = wsn_l + dl * 100 + h * 16;
            const float* Wc = W + h * 16 + fo;
#pragma unroll
            for (int k = 0; k < IN_FEAT; k++)
                acc = fmaf(wr[k], Wc[k * HF], acc);
        }
        float v = acc * (1.f / 6.f) + bias[fo];
        v = v > 0.f ? sc * v : sc * al * (__expf(v) - 1.f);
        out[2 * N_NODES + (size_t)(n0 + dl) * OUT_FEAT + fo] = v;
    }
}

// ---------------------------------------------------------------------------
// Workspace layout (float offsets):
//   [0, 600000)            a_src    (N*6)
//   [600000, 1200000)      a_dst    (N*6)
//   [1200000, 1204096)     gcursor  (NB ints, memsetAsync to 0 each launch)
//   [1204096, 3563392)     spack    (NB*CAP uints = 9.4 MB)
//   [3563392, 4363392)     data_f16 (N*16 halves = 3.2 MB)
//   [4363392, 13579392)    exf      (NBA*CAP*8 halves = 36.9 MB)
// Total ~54.3 MB.
// ---------------------------------------------------------------------------
extern "C" void kernel_launch(void* const* d_in, const int* in_sizes, int n_in,
                              void* d_out, int out_size, void* d_ws, size_t ws_size,
                              hipStream_t stream) {
    const float* data    = (const float*)d_in[0];
    const int*   eidx    = (const int*)d_in[1];      // int32 on device
    const float* W       = (const float*)d_in[2];
    const float* att_src = (const float*)d_in[3];
    const float* att_dst = (const float*)d_in[4];
    const float* bias    = (const float*)d_in[5];
    float*       out     = (float*)d_out;
    float*       ws      = (float*)d_ws;

    float*          a_src    = ws;
    float*          a_dst    = ws + 600000;
    int*            gcursor  = (int*)(ws + 1200000);
    unsigned int*   spack    = (unsigned int*)(ws + 1204096);
    unsigned short* data_f16 = (unsigned short*)(ws + 3563392);
    unsigned short* exf      = (unsigned short*)(ws + 4363392);

    hipMemsetAsync(gcursor, 0, NB * sizeof(int), stream);

    prep<<<NBLK_PART + NT_BLOCKS, 256, 0, stream>>>(
        eidx, eidx + N_EDGES, gcursor, spack,
        data, W, att_src, att_dst, a_src, a_dst, data_f16);

    edge_ex<<<(NBA * CAP) / 256, 256, 0, stream>>>(
        gcursor, spack, a_src, a_dst, exf);

    bucket_accumulate<<<NBA, 256, 0, stream>>>(
        gcursor, spack, data, data_f16, exf, W, bias, out);
}

// Round 14
// 155.130 us; speedup vs baseline: 1.2737x; 1.2737x over previous
//
#include <hip/hip_runtime.h>
#include <hip/hip_fp16.h>
#include <math.h>

#define N_NODES 100000
#define N_EDGES 1600000
#define E_TOT (N_EDGES + N_NODES)   // self-loops injected as virtual edges
#define IN_FEAT 16
#define OUT_FEAT 16
#define HEADS 6
#define HF 96                 // HEADS*OUT_FEAT

// Bucketed-aggregate geometry:
#define NB 4096               // histogram bins in prep (4000 used)
#define NBA 4000              // active buckets (4000*25 = 100000 exactly)
#define NPB 25                // nodes per bucket
#define CAP 576               // per-bucket capacity: mean 425 incl self, +7.3 sigma
#define MAXDEG 64             // per-node slot capacity (1+Poisson(16): P(>=63) ~ 1e-20)
#define NBLK_PART 256         // partition blocks
#define NT_BLOCKS ((N_NODES * HEADS + 255) / 256)

static __device__ __forceinline__ unsigned int pk2h(float a, float b) {
    return (unsigned int)__half_as_ushort(__float2half_rn(a))
         | ((unsigned int)__half_as_ushort(__float2half_rn(b)) << 16);
}

// ---------------------------------------------------------------------------
// K1: prep = partition (blocks [0,NBLK_PART)) + node_transform (rest).
// a_src/a_dst now stored with stride 8 (pads zeroed) so the hot kernel can
// do single masked 4B loads at s*8+h with an in-bounds tail row.
// spack[pos] = src | (d_local << 17).
// ---------------------------------------------------------------------------
__global__ void prep(const int* __restrict__ esrc,
                     const int* __restrict__ edst,
                     int* __restrict__ gcursor,
                     unsigned int* __restrict__ spack,
                     const float* __restrict__ data,
                     const float* __restrict__ W,
                     const float* __restrict__ att_src,
                     const float* __restrict__ att_dst,
                     float* __restrict__ a_srcF,
                     float* __restrict__ a_dstF,
                     unsigned short* __restrict__ data_f16) {
    __shared__ int shmem[2 * NB];   // 32 KB

    if (blockIdx.x < NBLK_PART) {
        // ---------------- partition branch ----------------
        int* hist = shmem;
        int* base = shmem + NB;
        const int chunk = (E_TOT + NBLK_PART - 1) / NBLK_PART;   // 6641
        const int e0 = blockIdx.x * chunk;
        const int e1 = min(e0 + chunk, E_TOT);

        for (int j = threadIdx.x; j < NB; j += blockDim.x) hist[j] = 0;
        __syncthreads();
        for (int e = e0 + threadIdx.x; e < e1; e += blockDim.x) {
            int d = (e < N_EDGES) ? edst[e] : (e - N_EDGES);
            atomicAdd(&hist[d / NPB], 1);      // native int ds_add
        }
        __syncthreads();
        for (int j = threadIdx.x; j < NB; j += blockDim.x) {
            int c = hist[j];
            base[j] = c ? atomicAdd(&gcursor[j], c) : 0;
        }
        __syncthreads();
        for (int j = threadIdx.x; j < NB; j += blockDim.x) hist[j] = 0;
        __syncthreads();
        for (int e = e0 + threadIdx.x; e < e1; e += blockDim.x) {
            int s, d;
            if (e < N_EDGES) { s = esrc[e]; d = edst[e]; }
            else             { s = d = e - N_EDGES; }
            int b = d / NPB;
            int r = atomicAdd(&hist[b], 1);
            int pos = b * CAP + base[b] + r;
            if (pos < (b + 1) * CAP)           // statistically unreachable
                spack[pos] = (unsigned int)s | ((unsigned int)(d - b * NPB) << 17);
        }
    } else {
        // ---------------- node_transform branch ----------------
        float* sW  = (float*)shmem;            // 1536 floats
        float* sAs = sW + IN_FEAT * HF;        // 96
        float* sAd = sAs + HF;                 // 96
        for (int i = threadIdx.x; i < IN_FEAT * HF; i += blockDim.x) sW[i] = W[i];
        for (int i = threadIdx.x; i < HF; i += blockDim.x) { sAs[i] = att_src[i]; sAd[i] = att_dst[i]; }
        __syncthreads();

        int gid = (blockIdx.x - NBLK_PART) * blockDim.x + threadIdx.x;
        int n = gid / HEADS;
        int h = gid % HEADS;
        if (n >= N_NODES) return;

        float dv[IN_FEAT];
        const float4* dp = (const float4*)(data + (size_t)n * IN_FEAT);
#pragma unroll
        for (int q = 0; q < 4; q++) {
            float4 v = dp[q];
            dv[q*4+0] = v.x; dv[q*4+1] = v.y; dv[q*4+2] = v.z; dv[q*4+3] = v.w;
        }

        // emit f16 copy of the row (threads h=0..3 each pack 4 halves)
        if (h < 4) {
            uint2 pkd;
            pkd.x = pk2h(dv[h*4+0], dv[h*4+1]);
            pkd.y = pk2h(dv[h*4+2], dv[h*4+3]);
            *(uint2*)(data_f16 + (size_t)n * IN_FEAT + h * 4) = pkd;
        }

        float outv[OUT_FEAT];
#pragma unroll
        for (int fo = 0; fo < OUT_FEAT; fo++) outv[fo] = 0.f;
#pragma unroll
        for (int k = 0; k < IN_FEAT; k++) {
            float dk = dv[k];
            const float* wrow = &sW[k * HF + h * OUT_FEAT];
#pragma unroll
            for (int fo = 0; fo < OUT_FEAT; fo++) outv[fo] = fmaf(dk, wrow[fo], outv[fo]);
        }

        float as = 0.f, ad = 0.f;
#pragma unroll
        for (int fo = 0; fo < OUT_FEAT; fo++) {
            as = fmaf(outv[fo], sAs[h * OUT_FEAT + fo], as);
            ad = fmaf(outv[fo], sAd[h * OUT_FEAT + fo], ad);
        }
        a_srcF[n * 8 + h] = as;
        a_dstF[n * 8 + h] = ad;
        if (h == 0) {                          // zero the pads
            a_srcF[n * 8 + 6] = 0.f; a_srcF[n * 8 + 7] = 0.f;
            a_dstF[n * 8 + 6] = 0.f; a_dstF[n * 8 + 7] = 0.f;
        }
    }
}

// ---------------------------------------------------------------------------
// K2: bucket accumulate v6 — R12 structure (3 barriers, fixed-slot binning,
// dynamic ticketing, (256,4) — R11/R13 proved anything tighter spills), with
// the redundant-exp fixed by LANE-SPECIALIZED exp + wave shfl broadcast:
//   lane slot*16+h (h<6) computes exp(leakyrelu(a_srcF[s*8+h]+adh)) for its
//   (slot, head) — ONE masked load + ONE exp chain per lane instead of every
//   lane redoing all 6 heads (~24 VALU saved/iter). 6 shfls per iteration
//   cover 4 edges (R9's failure was 6 shfl per SINGLE edge). ad[6] array ->
//   scalar adh (-5 VGPR; target <=63, the m69 occupancy-halving boundary).
// ---------------------------------------------------------------------------
__global__ __launch_bounds__(256, 4)
void bucket_accumulate(const int* __restrict__ gcursor,
                       const unsigned int* __restrict__ spack,
                       const float* __restrict__ data,
                       const unsigned short* __restrict__ data_f16,
                       const float* __restrict__ a_srcF,
                       const float* __restrict__ a_dstF,
                       const float* __restrict__ W,
                       const float* __restrict__ bias,
                       float* __restrict__ out) {
    const int b = blockIdx.x;
    const int n0 = b * NPB;
    __shared__ unsigned int olist[NPB * MAXDEG];   // 6.4 KB
    __shared__ float wsn_l[NPB * 100];             // 10 KB, pad stride 100
    __shared__ int cnt[NPB];
    __shared__ int nidx;

    const int tid  = threadIdx.x;
    const int lane = tid & 63;
    const int slot = lane >> 4;       // 4 edge-slots per wave
    const int f    = lane & 15;       // feature index
    const int sbase = lane & 48;      // slot*16 (shfl source base)

    int ecnt = gcursor[b];
    if (ecnt > CAP) ecnt = CAP;

    for (int j = tid; j < NPB; j += 256) cnt[j] = 0;
    if (tid == 0) nidx = 0;
    __syncthreads();

    // ---- single-pass bin into fixed per-node slots ----
    for (int i = tid; i < ecnt; i += 256) {
        unsigned int p = spack[b * CAP + i];
        int dl = (int)(p >> 17);
        int r = atomicAdd(&cnt[dl], 1);
        if (r < MAXDEG)                // statistically unreachable guard
            olist[dl * MAXDEG + r] = p & 0x1FFFFu;
    }
    __syncthreads();

    // ---- phase A: dynamic node->wave assignment ----
    for (;;) {
        int my;
        if (lane == 0) my = atomicAdd(&nidx, 1);
        my = __builtin_amdgcn_readfirstlane(my);
        if (my >= NPB) break;

        int T = cnt[my];
        if (T > MAXDEG) T = MAXDEG;
        const unsigned int* ol = olist + my * MAXDEG;

        float adh = 0.f;
        if (f < HEADS) adh = a_dstF[(n0 + my) * 8 + f];

        float ws[HEADS], dn[HEADS];
#pragma unroll
        for (int h = 0; h < HEADS; h++) { ws[h] = 0.f; dn[h] = 0.f; }

        for (int t = slot; t < T; t += 4) {
            int s = (int)ol[t];
            float dv = __half2float(__ushort_as_half(data_f16[(size_t)s * IN_FEAT + f]));
            float exv = 0.f;
            if (f < HEADS) {                       // lane f computes head f
                float e = a_srcF[s * 8 + f] + adh;
                e = fmaxf(e, 0.2f * e);            // leaky relu
                exv = __expf(e);
            }
            float e0 = __shfl(exv, sbase + 0);
            float e1 = __shfl(exv, sbase + 1);
            float e2 = __shfl(exv, sbase + 2);
            float e3 = __shfl(exv, sbase + 3);
            float e4 = __shfl(exv, sbase + 4);
            float e5 = __shfl(exv, sbase + 5);
            ws[0] = fmaf(dv, e0, ws[0]); dn[0] += e0;
            ws[1] = fmaf(dv, e1, ws[1]); dn[1] += e1;
            ws[2] = fmaf(dv, e2, ws[2]); dn[2] += e2;
            ws[3] = fmaf(dv, e3, ws[3]); dn[3] += e3;
            ws[4] = fmaf(dv, e4, ws[4]); dn[4] += e4;
            ws[5] = fmaf(dv, e5, ws[5]); dn[5] += e5;
        }

        // butterfly over the 4 slots -> every lane holds totals
#pragma unroll
        for (int h = 0; h < HEADS; h++) {
            ws[h] += __shfl_xor(ws[h], 16);
            ws[h] += __shfl_xor(ws[h], 32);
            dn[h] += __shfl_xor(dn[h], 16);
            dn[h] += __shfl_xor(dn[h], 32);
        }

        if (slot == 0) {
            const int n = n0 + my;
            float cs = 0.f;
#pragma unroll
            for (int h = 0; h < HEADS; h++) {
                float wsn = ws[h] * __builtin_amdgcn_rcpf(dn[h] + 1e-16f);
                cs += wsn;
                wsn_l[my * 100 + h * 16 + f] = wsn;
            }
            if (f < 2) {                      // fused coord output (f32 key)
                float c = cs * (0.2f / 6.f);
                float key = data[(size_t)n * IN_FEAT + f];
                if (key == 1.0f)      c = 1.0f;
                else if (key == 0.0f) c = 0.0f;
                out[n * 2 + f] = c;
            }
        }
    }
    __syncthreads();

    // ---- phase B: dense per-node transform; W via L1 (6 KB, hot) ----
    const float sc = 1.0507009873554805f;
    const float al = 1.6732632423543772f;
    for (int task = tid; task < NPB * 16; task += 256) {
        int dl = task >> 4, fo = task & 15;
        float acc = 0.f;
#pragma unroll
        for (int h = 0; h < HEADS; h++) {
            const float* wr = wsn_l + dl * 100 + h * 16;
            const float* Wc = W + h * 16 + fo;
#pragma unroll
            for (int k = 0; k < IN_FEAT; k++)
                acc = fmaf(wr[k], Wc[k * HF], acc);
        }
        float v = acc * (1.f / 6.f) + bias[fo];
        v = v > 0.f ? sc * v : sc * al * (__expf(v) - 1.f);
        out[2 * N_NODES + (size_t)(n0 + dl) * OUT_FEAT + fo] = v;
    }
}

// ---------------------------------------------------------------------------
// Workspace layout (float offsets):
//   [0, 800008)            a_srcF   (N*8 + 8 pad tail)
//   [800008, 1600016)      a_dstF   (N*8 + 8 pad tail)
//   [1600016, 1604112)     gcursor  (NB ints, memsetAsync to 0 each launch)
//   [1604112, 3963408)     spack    (NB*CAP uints = 9.4 MB)
//   [3963408, 4763408)     data_f16 (N*16 halves = 3.2 MB)
// Total ~19 MB.
// ---------------------------------------------------------------------------
extern "C" void kernel_launch(void* const* d_in, const int* in_sizes, int n_in,
                              void* d_out, int out_size, void* d_ws, size_t ws_size,
                              hipStream_t stream) {
    const float* data    = (const float*)d_in[0];
    const int*   eidx    = (const int*)d_in[1];      // int32 on device
    const float* W       = (const float*)d_in[2];
    const float* att_src = (const float*)d_in[3];
    const float* att_dst = (const float*)d_in[4];
    const float* bias    = (const float*)d_in[5];
    float*       out     = (float*)d_out;
    float*       ws      = (float*)d_ws;

    float*          a_srcF   = ws;
    float*          a_dstF   = ws + 800008;
    int*            gcursor  = (int*)(ws + 1600016);
    unsigned int*   spack    = (unsigned int*)(ws + 1604112);
    unsigned short* data_f16 = (unsigned short*)(ws + 3963408);

    hipMemsetAsync(gcursor, 0, NB * sizeof(int), stream);

    prep<<<NBLK_PART + NT_BLOCKS, 256, 0, stream>>>(
        eidx, eidx + N_EDGES, gcursor, spack,
        data, W, att_src, att_dst, a_srcF, a_dstF, data_f16);

    bucket_accumulate<<<NBA, 256, 0, stream>>>(
        gcursor, spack, data, data_f16, a_srcF, a_dstF, W, bias, out);
}